// Round 14
// baseline (5985.919 us; speedup 1.0000x reference)
//
#include <hip/hip_runtime.h>
#include <float.h>

#define N_PTS 16384
#define M_PTS 4096
#define K_NN  16
#define CIN   64
#define COUT  64
#define MAGIC 0x600DF00Du

typedef float v2f __attribute__((ext_vector_type(2)));
typedef unsigned long long ull;

// Exact f32 rounding to match numpy/jax: ((dx*dx + dy*dy) + dz*dz), no fma contraction.
__device__ __forceinline__ float dist2_exact(float ax, float ay, float az,
                                             float bx, float by, float bz) {
    float dx = __fsub_rn(ax, bx);
    float dy = __fsub_rn(ay, by);
    float dz = __fsub_rn(az, bz);
    return __fadd_rn(__fadd_rn(__fmul_rn(dx, dx), __fmul_rn(dy, dy)), __fmul_rn(dz, dz));
}

// Packed f32 ops via inline asm (v2f codegen otherwise scalarizes — R6 evidence).
__device__ __forceinline__ v2f pk_add(v2f a, v2f b) {
    v2f d; asm("v_pk_add_f32 %0, %1, %2" : "=v"(d) : "v"(a), "v"(b)); return d;
}
__device__ __forceinline__ v2f pk_mul(v2f a, v2f b) {
    v2f d; asm("v_pk_mul_f32 %0, %1, %2" : "=v"(d) : "v"(a), "v"(b)); return d;
}

// ---- DPP wave-64 reduction steps (idempotent ops -> full masks safe) ----
template <int CTRL>
__device__ __forceinline__ float dpp_fmax_step(float x) {
    int xi = __float_as_int(x);
    int yi = __builtin_amdgcn_update_dpp(xi, xi, CTRL, 0xf, 0xf, false);
    return fmaxf(x, __int_as_float(yi));
}
template <int CTRL>
__device__ __forceinline__ unsigned dpp_umin_step(unsigned x) {
    int xi = (int)x;
    unsigned y = (unsigned)__builtin_amdgcn_update_dpp(xi, xi, CTRL, 0xf, 0xf, false);
    return y < x ? y : x;
}
template <int CTRL>
__device__ __forceinline__ ull dpp_u64max_step(ull x) {
    int lo = (int)(unsigned)x;
    int hi = (int)(unsigned)(x >> 32);
    unsigned olo = (unsigned)__builtin_amdgcn_update_dpp(lo, lo, CTRL, 0xf, 0xf, false);
    unsigned ohi = (unsigned)__builtin_amdgcn_update_dpp(hi, hi, CTRL, 0xf, 0xf, false);
    ull o = ((ull)ohi << 32) | (ull)olo;
    return o > x ? o : x;
}
__device__ __forceinline__ unsigned wave_umin(unsigned x) {
    x = dpp_umin_step<0x111>(x);
    x = dpp_umin_step<0x112>(x);
    x = dpp_umin_step<0x114>(x);
    x = dpp_umin_step<0x118>(x);
    x = dpp_umin_step<0x142>(x);
    x = dpp_umin_step<0x143>(x);
    return (unsigned)__builtin_amdgcn_readlane((int)x, 63);
}

// Per-wave record extraction (R9, unchanged): wave max of d2 -> SGPR record.
#define EXTRACT_RECORD()                                                          \
    {                                                                             \
        float _w = bv;                                                            \
        _w = dpp_fmax_step<0x111>(_w);                                            \
        _w = dpp_fmax_step<0x112>(_w);                                            \
        _w = dpp_fmax_step<0x114>(_w);                                            \
        _w = dpp_fmax_step<0x118>(_w);                                            \
        _w = dpp_fmax_step<0x142>(_w);                                            \
        _w = dpp_fmax_step<0x143>(_w);                                            \
        my_wval = __int_as_float(__builtin_amdgcn_readlane(__float_as_int(_w), 63)); \
        unsigned _kk = 0xffffffffu;                                               \
        float _cz = 0.0f;                                                         \
        _Pragma("unroll")                                                         \
        for (int _u = 0; _u < 16; ++_u) {                                         \
            const float _dv = (_u & 1) ? d2[_u >> 1].y : d2[_u >> 1].x;           \
            const unsigned _og = (_u & 1) ? (opk[_u >> 1] >> 16)                  \
                                          : (opk[_u >> 1] & 0xffffu);             \
            const unsigned _ky = (_og << 4) | (unsigned)_u;                       \
            const unsigned _uk = (_dv == my_wval) ? _ky : 0xffffffffu;            \
            if (_uk < _kk) {                                                      \
                _kk = _uk;                                                        \
                _cz = (_u & 1) ? zp[_u >> 1].y : zp[_u >> 1].x;                   \
            }                                                                     \
        }                                                                         \
        const unsigned _wkk = wave_umin(_kk);                                     \
        const ull _m = __ballot(_kk == _wkk);                                     \
        const int _wl = (int)__builtin_ctzll(_m);                                 \
        my_orig = _wkk >> 4;                                                      \
        const int _slot = (int)(_wkk & 15u);                                      \
        const int _wt = wv * 64 + _wl;                                            \
        const float4 _xy = s_xy4[_wt * 9 + (_slot >> 1)];                         \
        const float _qx = (_slot & 1) ? _xy.y : _xy.x;                            \
        const float _qy = (_slot & 1) ? _xy.w : _xy.z;                            \
        my_qx = __int_as_float(__builtin_amdgcn_readfirstlane(__float_as_int(_qx))); \
        my_qy = __int_as_float(__builtin_amdgcn_readfirstlane(__float_as_int(_qy))); \
        my_qz = __int_as_float(__builtin_amdgcn_readlane(__float_as_int(_cz), _wl)); \
    }

// ---------------------------------------------------------------------------
// Fused-serial kernel (R14). Block 0 = EXACT R9 fps (no in-loop fences/flags),
// one release flag at the very end. Blocks 1..128 = consumers: stage W, then
// sleep-poll the single flag; after fps completes, knn+vn for 32 queries each
// across 128 CUs (~100 µs tail vs R12's 444 µs of knn+vn+launch gaps).
// ---------------------------------------------------------------------------
__global__ __launch_bounds__(1024)
void fused_kernel(const float* __restrict__ p, const float* __restrict__ x,
                  const float* __restrict__ Wf, const float* __restrict__ Wd,
                  float* __restrict__ out, unsigned* __restrict__ flags) {
#pragma clang fp contract(off)
    __shared__ __align__(16) char SMEM[160384];
    const int t = threadIdx.x;
    const int lane = t & 63, wv = t >> 6;

    if (blockIdx.x == 0) {
        // ================= producer: R9 fps (measured floor) =================
        ull* keys = (ull*)SMEM;
        float4* s_xy4 = (float4*)SMEM;
        float* s_pick = (float*)(SMEM + 147456);
        float4* s_recf = (float4*)(SMEM + 147456 + 12288);     // [2][16]
        unsigned* s_reco = (unsigned*)(SMEM + 147456 + 12288 + 512);

        // ---- Phase A: bitonic sort by x ----
        for (int u = 0; u < 16; ++u) {
            const int j = u * 1024 + t;
            keys[j] = ((ull)__float_as_uint(p[3 * j]) << 32) | (unsigned)j;
        }
        __syncthreads();
        for (int k = 2; k <= N_PTS; k <<= 1) {
            for (int j = k >> 1; j > 0; j >>= 1) {
                for (int e = 0; e < 8; ++e) {
                    const int c = e * 1024 + t;
                    const int i1 = 2 * c - (c & (j - 1));
                    const int i2 = i1 + j;
                    const ull a = keys[i1], b = keys[i2];
                    const bool up = ((i1 & k) == 0);
                    if ((a > b) == up) { keys[i1] = b; keys[i2] = a; }
                }
                __syncthreads();
            }
        }

        unsigned opk[8];
#pragma unroll
        for (int u = 0; u < 8; ++u) {
            const ull a = keys[t * 16 + 2 * u];
            const ull b = keys[t * 16 + 2 * u + 1];
            opk[u] = ((unsigned)a & 0xffffu) | (((unsigned)b & 0xffffu) << 16);
        }
        __syncthreads();

        v2f zp[8], d2[8];
        const float q0x = p[0], q0y = p[1], q0z = p[2];
        float bv = -1.0f;
        float xf = 0.0f, xl = 0.0f;
#pragma unroll
        for (int u = 0; u < 8; ++u) {
            const int o0 = (int)(opk[u] & 0xffffu), o1 = (int)(opk[u] >> 16);
            const float x0 = p[3 * o0], y0 = p[3 * o0 + 1], z0 = p[3 * o0 + 2];
            const float x1 = p[3 * o1], y1 = p[3 * o1 + 1], z1 = p[3 * o1 + 2];
            s_xy4[t * 9 + u] = make_float4(x0, x1, y0, y1);
            zp[u] = (v2f){z0, z1};
            d2[u] = (v2f){dist2_exact(x0, y0, z0, q0x, q0y, q0z),
                          dist2_exact(x1, y1, z1, q0x, q0y, q0z)};
            bv = fmaxf(bv, fmaxf(d2[u].x, d2[u].y));
            if (u == 0) xf = x0;
            if (u == 7) xl = x1;
        }
        const float wxmin = __int_as_float(__builtin_amdgcn_readlane(__float_as_int(xf), 0));
        const float wxmax = __int_as_float(__builtin_amdgcn_readlane(__float_as_int(xl), 63));
        const float cx = 0.5f * (wxmin + wxmax);
        const float hw_safe = 0.5f * (wxmax - wxmin) + 1e-5f;

        float my_wval, my_qx, my_qy, my_qz;
        unsigned my_orig;
        EXTRACT_RECORD();
        if (lane == 0) {
            s_recf[16 + wv] = make_float4(my_wval, my_qx, my_qy, my_qz);
            s_reco[16 + wv] = my_orig;
        }
        if (t == 0) { s_pick[0] = q0x; s_pick[1] = q0y; s_pick[2] = q0z; }

        for (int i = 1; i < M_PTS; ++i) {
            const int par = i & 1;
            __syncthreads();                           // the ONE barrier per iteration

            // ring flush: once per 512 iters (prev 512 picks, other ring half)
            if ((i & 511) == 0) {
                const int b = (i - 512) & 1023;
                const int base3 = (i - 512) * 3;
                out[base3 + t] = s_pick[b * 3 + t];
                if (t < 512) out[base3 + 1024 + t] = s_pick[b * 3 + 1024 + t];
            }

            // global winner from the 16 records
            const int r = lane & 15;
            const float4 rf = s_recf[par * 16 + r];
            const unsigned ro = s_reco[par * 16 + r];
            ull key = ((ull)__float_as_uint(rf.x) << 32) | (ull)(~ro);
            ull red = key;
            red = dpp_u64max_step<0x111>(red);
            red = dpp_u64max_step<0x112>(red);
            red = dpp_u64max_step<0x114>(red);
            red = dpp_u64max_step<0x118>(red);
            const unsigned wlo = (unsigned)__builtin_amdgcn_readlane((int)(unsigned)red, 63);
            const unsigned whi = (unsigned)__builtin_amdgcn_readlane((int)(unsigned)(red >> 32), 63);
            const ull wk = ((ull)whi << 32) | (ull)wlo;
            const ull hm = __ballot(key == wk);
            const int hl = (int)__builtin_ctzll(hm);
            const float qx = __int_as_float(__builtin_amdgcn_readlane(__float_as_int(rf.y), hl));
            const float qy = __int_as_float(__builtin_amdgcn_readlane(__float_as_int(rf.z), hl));
            const float qz = __int_as_float(__builtin_amdgcn_readlane(__float_as_int(rf.w), hl));
            if (t == 0) {
                const int s3 = (i & 1023) * 3;
                s_pick[s3] = qx; s_pick[s3 + 1] = qy; s_pick[s3 + 2] = qz;
            }

            // x-slab prune
            const float dxq = fabsf(qx - cx);
            bool active = true;
            if (dxq > hw_safe) {
                const float lb = dxq - hw_safe;
                active = (lb * lb <= my_wval);
            }
            if (active) {
                const v2f nqx2 = (v2f){-qx, -qx};
                const v2f nqy2 = (v2f){-qy, -qy};
                const v2f nqz2 = (v2f){-qz, -qz};
                bv = -1.0f;
#pragma unroll
                for (int u = 0; u < 8; ++u) {
                    const float4 xy = s_xy4[t * 9 + u];
                    const v2f xp = (v2f){xy.x, xy.y};
                    const v2f yp = (v2f){xy.z, xy.w};
                    const v2f dx = pk_add(xp, nqx2);
                    const v2f dy = pk_add(yp, nqy2);
                    const v2f dz = pk_add(zp[u], nqz2);
                    const v2f m1 = pk_mul(dx, dx);
                    const v2f m2 = pk_mul(dy, dy);
                    const v2f m3 = pk_mul(dz, dz);
                    const v2f s = pk_add(pk_add(m1, m2), m3);
                    d2[u] = __builtin_elementwise_min(d2[u], s);
                    bv = fmaxf(bv, fmaxf(d2[u].x, d2[u].y));
                }
                EXTRACT_RECORD();
            }
            if (lane == 0) {
                s_recf[(1 - par) * 16 + wv] = make_float4(my_wval, my_qx, my_qy, my_qz);
                s_reco[(1 - par) * 16 + wv] = my_orig;
            }
        }

        // final flush: picks 3584..4095 + n_o, then publish the single flag
        __syncthreads();
        {
            const int base3 = 3584 * 3;
            const int b3 = 512 * 3;
            out[base3 + t] = s_pick[b3 + t];
            if (t < 512) out[base3 + 1024 + t] = s_pick[b3 + 1024 + t];
            if (t == 0) out[12288 + 786432] = 4096.0f;
        }
        __syncthreads();                               // drain ALL waves' stores
        if (t == 0) {
            __threadfence();                           // one-time, off the loop
            __hip_atomic_store(&flags[0], MAGIC,
                               __ATOMIC_RELEASE, __HIP_MEMORY_SCOPE_AGENT);
        }
    } else {
        // ================= consumers: knn + vn after fps =================
        float* sWf = (float*)SMEM;                     // 16 KB  [c*64+o]
        float* sWd = (float*)(SMEM + 16384);           // 16 KB
        float* sg  = (float*)(SMEM + 32768);           // 96 KB  8 q x 16 k x 192
        int*  s_nn = (int*)(SMEM + 131072);            // 2 KB   32 q x 16

        const int cj = (int)blockIdx.x - 1;
        const int qbase = cj * 32;                     // 128 blocks x 32 = 4096

        // stage W transposed during the wait (independent of picks)
        for (int u = t; u < CIN * COUT; u += 1024) {
            const int o = u >> 6, c = u & 63;
            sWf[c * 64 + o] = Wf[u];
            sWd[c * 64 + o] = Wd[u];
        }

        if (t == 0) {
            while (__hip_atomic_load(&flags[0], __ATOMIC_ACQUIRE,
                                     __HIP_MEMORY_SCOPE_AGENT) != MAGIC)
                __builtin_amdgcn_s_sleep(64);          // low-rate polling
        }
        __syncthreads();                               // all picks now visible

        // ---- knn: one wave per query (2 rounds), results into LDS ----
        for (int qq = wv; qq < 32; qq += 16) {
            const int m = qbase + qq;
            const float qx = out[3 * m], qy = out[3 * m + 1], qz = out[3 * m + 2];
            const float qq2 = __fadd_rn(__fadd_rn(__fmul_rn(qx, qx), __fmul_rn(qy, qy)),
                                        __fmul_rn(qz, qz));
            float D[16]; int I[16];
#pragma unroll
            for (int s = 0; s < 16; ++s) { D[s] = FLT_MAX; I[s] = 0x7fffffff; }
            for (int c = 0; c < N_PTS / 64; ++c) {
                const int j = c * 64 + lane;
                const float px = p[3 * j], py = p[3 * j + 1], pz = p[3 * j + 2];
                const float pp = __fadd_rn(__fadd_rn(__fmul_rn(px, px), __fmul_rn(py, py)),
                                           __fmul_rn(pz, pz));
                const float qp = __fadd_rn(__fadd_rn(__fmul_rn(qx, px), __fmul_rn(qy, py)),
                                           __fmul_rn(qz, pz));
                const float d = __fadd_rn(__fsub_rn(qq2, __fmul_rn(2.0f, qp)), pp);
                if (d < D[15]) {
                    D[15] = d; I[15] = j;
#pragma unroll
                    for (int s = 15; s > 0; --s) {
                        if (D[s] < D[s - 1]) {
                            float tf = D[s]; D[s] = D[s - 1]; D[s - 1] = tf;
                            int   ti = I[s]; I[s] = I[s - 1]; I[s - 1] = ti;
                        }
                    }
                }
            }
            int myout = 0;
            for (int r = 0; r < 16; ++r) {
                float v = D[0]; int ix = I[0]; int bl = lane;
#pragma unroll
                for (int off = 1; off < 64; off <<= 1) {
                    float ov = __shfl_xor(v, off);
                    int   oi = __shfl_xor(ix, off);
                    int   ol = __shfl_xor(bl, off);
                    if (ov < v || (ov == v && oi < ix)) { v = ov; ix = oi; bl = ol; }
                }
                if (lane == bl) {
#pragma unroll
                    for (int s = 0; s < 15; ++s) { D[s] = D[s + 1]; I[s] = I[s + 1]; }
                    D[15] = FLT_MAX; I[15] = 0x7fffffff;
                }
                if (lane == r) myout = ix;
            }
            if (lane < K_NN) s_nn[qq * K_NN + lane] = myout;
        }
        __syncthreads();

        // ---- vn: 8 queries per round, thread (qi,o) in [0,512) ----
        float* xo = out + 12288;
        for (int r0 = 0; r0 < 32; r0 += 8) {
            __syncthreads();                           // protect sg reuse
            for (int idx = t; idx < 8 * K_NN * 192; idx += 1024) {
                const int pair = idx / 192;            // qi*16 + k
                const int c3 = idx - pair * 192;
                const int jn = s_nn[(r0 + (pair >> 4)) * K_NN + (pair & 15)];
                sg[idx] = x[jn * 192 + c3];
            }
            __syncthreads();
            if (t < 512) {
                const int qi = t >> 6, o = t & 63;
                const float* g = &sg[qi * K_NN * 192];
                float a0 = 0.0f, a1 = 0.0f, a2 = 0.0f;
                for (int k = 0; k < K_NN; ++k) {
                    const float* gk = &g[k * 192];
                    float q0 = 0.0f, q1 = 0.0f, q2 = 0.0f;
                    float d0 = 0.0f, d1 = 0.0f, d2v = 0.0f;
#pragma unroll 8
                    for (int c = 0; c < CIN; ++c) {
                        const float wf = sWf[c * 64 + o];
                        const float wd = sWd[c * 64 + o];
                        const float g0 = gk[c * 3], g1 = gk[c * 3 + 1], g2 = gk[c * 3 + 2];
                        q0 = fmaf(wf, g0, q0); q1 = fmaf(wf, g1, q1); q2 = fmaf(wf, g2, q2);
                        d0 = fmaf(wd, g0, d0); d1 = fmaf(wd, g1, d1); d2v = fmaf(wd, g2, d2v);
                    }
                    const float dot = q0 * d0 + q1 * d1 + q2 * d2v;
                    const float dns = d0 * d0 + d1 * d1 + d2v * d2v + 1e-6f;
                    const float f = (dot >= 0.0f) ? 0.0f : 0.8f * (dot / dns);
                    a0 += q0 - f * d0;
                    a1 += q1 - f * d1;
                    a2 += q2 - f * d2v;
                }
                const int m = qbase + r0 + qi;
                xo[(o * 3 + 0) * M_PTS + m] = a0 * 0.0625f;
                xo[(o * 3 + 1) * M_PTS + m] = a1 * 0.0625f;
                xo[(o * 3 + 2) * M_PTS + m] = a2 * 0.0625f;
            }
        }
    }
}

// ---------------------------------------------------------------------------
extern "C" void kernel_launch(void* const* d_in, const int* in_sizes, int n_in,
                              void* d_out, int out_size, void* d_ws, size_t ws_size,
                              hipStream_t stream) {
    const float* p  = (const float*)d_in[0];
    const float* x  = (const float*)d_in[1];
    const float* Wf = (const float*)d_in[2];
    const float* Wd = (const float*)d_in[3];
    float* out = (float*)d_out;
    unsigned* flags = (unsigned*)d_ws;     // 0xAA poison != MAGIC

    fused_kernel<<<129, 1024, 0, stream>>>(p, x, Wf, Wd, out, flags);
}

// Round 15
// 5543.410 us; speedup vs baseline: 1.0798x; 1.0798x over previous
//
#include <hip/hip_runtime.h>
#include <float.h>

#define N_PTS 16384
#define M_PTS 4096
#define K_NN  16
#define CIN   64
#define COUT  64

typedef float v2f __attribute__((ext_vector_type(2)));
typedef unsigned long long ull;

// Exact f32 rounding to match numpy/jax: ((dx*dx + dy*dy) + dz*dz), no fma contraction.
__device__ __forceinline__ float dist2_exact(float ax, float ay, float az,
                                             float bx, float by, float bz) {
    float dx = __fsub_rn(ax, bx);
    float dy = __fsub_rn(ay, by);
    float dz = __fsub_rn(az, bz);
    return __fadd_rn(__fadd_rn(__fmul_rn(dx, dx), __fmul_rn(dy, dy)), __fmul_rn(dz, dz));
}

// Packed f32 ops via inline asm (v2f codegen otherwise scalarizes — R6 evidence).
__device__ __forceinline__ v2f pk_add(v2f a, v2f b) {
    v2f d; asm("v_pk_add_f32 %0, %1, %2" : "=v"(d) : "v"(a), "v"(b)); return d;
}
__device__ __forceinline__ v2f pk_mul(v2f a, v2f b) {
    v2f d; asm("v_pk_mul_f32 %0, %1, %2" : "=v"(d) : "v"(a), "v"(b)); return d;
}

// ---- DPP wave-64 reduction steps (idempotent ops -> full masks safe) ----
template <int CTRL>
__device__ __forceinline__ float dpp_fmax_step(float x) {
    int xi = __float_as_int(x);
    int yi = __builtin_amdgcn_update_dpp(xi, xi, CTRL, 0xf, 0xf, false);
    return fmaxf(x, __int_as_float(yi));
}
template <int CTRL>
__device__ __forceinline__ unsigned dpp_umin_step(unsigned x) {
    int xi = (int)x;
    unsigned y = (unsigned)__builtin_amdgcn_update_dpp(xi, xi, CTRL, 0xf, 0xf, false);
    return y < x ? y : x;
}
template <int CTRL>
__device__ __forceinline__ ull dpp_u64max_step(ull x) {
    int lo = (int)(unsigned)x;
    int hi = (int)(unsigned)(x >> 32);
    unsigned olo = (unsigned)__builtin_amdgcn_update_dpp(lo, lo, CTRL, 0xf, 0xf, false);
    unsigned ohi = (unsigned)__builtin_amdgcn_update_dpp(hi, hi, CTRL, 0xf, 0xf, false);
    ull o = ((ull)ohi << 32) | (ull)olo;
    return o > x ? o : x;
}
__device__ __forceinline__ unsigned wave_umin(unsigned x) {
    x = dpp_umin_step<0x111>(x);
    x = dpp_umin_step<0x112>(x);
    x = dpp_umin_step<0x114>(x);
    x = dpp_umin_step<0x118>(x);
    x = dpp_umin_step<0x142>(x);
    x = dpp_umin_step<0x143>(x);
    return (unsigned)__builtin_amdgcn_readlane((int)x, 63);
}

// Per-wave record extraction (R9, unchanged): wave max of d2 -> SGPR record.
#define EXTRACT_RECORD()                                                          \
    {                                                                             \
        float _w = bv;                                                            \
        _w = dpp_fmax_step<0x111>(_w);                                            \
        _w = dpp_fmax_step<0x112>(_w);                                            \
        _w = dpp_fmax_step<0x114>(_w);                                            \
        _w = dpp_fmax_step<0x118>(_w);                                            \
        _w = dpp_fmax_step<0x142>(_w);                                            \
        _w = dpp_fmax_step<0x143>(_w);                                            \
        my_wval = __int_as_float(__builtin_amdgcn_readlane(__float_as_int(_w), 63)); \
        unsigned _kk = 0xffffffffu;                                               \
        float _cz = 0.0f;                                                         \
        _Pragma("unroll")                                                         \
        for (int _u = 0; _u < 16; ++_u) {                                         \
            const float _dv = (_u & 1) ? d2[_u >> 1].y : d2[_u >> 1].x;           \
            const unsigned _og = (_u & 1) ? (opk[_u >> 1] >> 16)                  \
                                          : (opk[_u >> 1] & 0xffffu);             \
            const unsigned _ky = (_og << 4) | (unsigned)_u;                       \
            const unsigned _uk = (_dv == my_wval) ? _ky : 0xffffffffu;            \
            if (_uk < _kk) {                                                      \
                _kk = _uk;                                                        \
                _cz = (_u & 1) ? zp[_u >> 1].y : zp[_u >> 1].x;                   \
            }                                                                     \
        }                                                                         \
        const unsigned _wkk = wave_umin(_kk);                                     \
        const ull _m = __ballot(_kk == _wkk);                                     \
        const int _wl = (int)__builtin_ctzll(_m);                                 \
        my_orig = _wkk >> 4;                                                      \
        const int _slot = (int)(_wkk & 15u);                                      \
        const int _wt = wv * 64 + _wl;                                            \
        const float4 _xy = s_xy4[_wt * 9 + (_slot >> 1)];                         \
        const float _qx = (_slot & 1) ? _xy.y : _xy.x;                            \
        const float _qy = (_slot & 1) ? _xy.w : _xy.z;                            \
        my_qx = __int_as_float(__builtin_amdgcn_readfirstlane(__float_as_int(_qx))); \
        my_qy = __int_as_float(__builtin_amdgcn_readfirstlane(__float_as_int(_qy))); \
        my_qz = __int_as_float(__builtin_amdgcn_readlane(__float_as_int(_cz), _wl)); \
    }

// ---------------------------------------------------------------------------
// Kernel 1: furthest point sampling — EXACT R9/R12 kernel, standalone dispatch
// (R13/R14 proved co-residency costs the serial chain ~15%; alone = 5155 µs).
// ---------------------------------------------------------------------------
__global__ __launch_bounds__(1024) void fps_kernel(const float* __restrict__ p,
                                                   float* __restrict__ out) {
#pragma clang fp contract(off)
    const int t = threadIdx.x;
    const int lane = t & 63, wv = t >> 6;
    __shared__ char smem[147456];                      // keys[16384] then s_xy4[1024*9]
    __shared__ float s_pick[1024 * 3];                 // pick ring (12 KB)
    __shared__ float4 s_recf[2][16];                   // {val, qx, qy, qz}
    __shared__ unsigned s_reco[2][16];                 // orig

    ull* keys = (ull*)smem;
    float4* s_xy4 = (float4*)smem;

    // ---- Phase A: bitonic sort by x (keys unique via idx bits) ----
    for (int u = 0; u < 16; ++u) {
        const int j = u * 1024 + t;
        keys[j] = ((ull)__float_as_uint(p[3 * j]) << 32) | (unsigned)j;
    }
    __syncthreads();
    for (int k = 2; k <= N_PTS; k <<= 1) {
        for (int j = k >> 1; j > 0; j >>= 1) {
            for (int e = 0; e < 8; ++e) {
                const int c = e * 1024 + t;
                const int i1 = 2 * c - (c & (j - 1));
                const int i2 = i1 + j;
                const ull a = keys[i1], b = keys[i2];
                const bool up = ((i1 & k) == 0);
                if ((a > b) == up) { keys[i1] = b; keys[i2] = a; }
            }
            __syncthreads();
        }
    }

    // read own 16 sorted keys -> packed original indices (8 regs)
    unsigned opk[8];
#pragma unroll
    for (int u = 0; u < 8; ++u) {
        const ull a = keys[t * 16 + 2 * u];
        const ull b = keys[t * 16 + 2 * u + 1];
        opk[u] = ((unsigned)a & 0xffffu) | (((unsigned)b & 0xffffu) << 16);
    }
    __syncthreads();                                   // all key reads done before overwrite

    // ---- gather coords, build LDS xy ({x0,x1,y0,y1}) + reg z/d2, init bv ----
    v2f zp[8], d2[8];
    const float q0x = p[0], q0y = p[1], q0z = p[2];
    float bv = -1.0f;
    float xf = 0.0f, xl = 0.0f;
#pragma unroll
    for (int u = 0; u < 8; ++u) {
        const int o0 = (int)(opk[u] & 0xffffu), o1 = (int)(opk[u] >> 16);
        const float x0 = p[3 * o0], y0 = p[3 * o0 + 1], z0 = p[3 * o0 + 2];
        const float x1 = p[3 * o1], y1 = p[3 * o1 + 1], z1 = p[3 * o1 + 2];
        s_xy4[t * 9 + u] = make_float4(x0, x1, y0, y1);
        zp[u] = (v2f){z0, z1};
        d2[u] = (v2f){dist2_exact(x0, y0, z0, q0x, q0y, q0z),
                      dist2_exact(x1, y1, z1, q0x, q0y, q0z)};
        bv = fmaxf(bv, fmaxf(d2[u].x, d2[u].y));
        if (u == 0) xf = x0;
        if (u == 7) xl = x1;
    }
    const float wxmin = __int_as_float(__builtin_amdgcn_readlane(__float_as_int(xf), 0));
    const float wxmax = __int_as_float(__builtin_amdgcn_readlane(__float_as_int(xl), 63));
    const float cx = 0.5f * (wxmin + wxmax);
    const float hw_safe = 0.5f * (wxmax - wxmin) + 1e-5f;

    float my_wval, my_qx, my_qy, my_qz;
    unsigned my_orig;
    EXTRACT_RECORD();
    if (lane == 0) {
        s_recf[1][wv] = make_float4(my_wval, my_qx, my_qy, my_qz);
        s_reco[1][wv] = my_orig;
    }
    if (t == 0) { s_pick[0] = q0x; s_pick[1] = q0y; s_pick[2] = q0z; }

    for (int i = 1; i < M_PTS; ++i) {
        const int par = i & 1;
        __syncthreads();                               // the ONE barrier per iteration

        // ring flush: once per 512 iters, previous 512-block (other ring half)
        if ((i & 511) == 0) {
            const int b = (i - 512) & 1023;
            const int base3 = (i - 512) * 3;
            out[base3 + t] = s_pick[b * 3 + t];
            if (t < 512) out[base3 + 1024 + t] = s_pick[b * 3 + 1024 + t];
        }

        // global winner from the 16 records: u64 key = (val_bits<<32 | ~orig)
        const int r = lane & 15;
        const float4 rf = s_recf[par][r];
        const unsigned ro = s_reco[par][r];
        ull key = ((ull)__float_as_uint(rf.x) << 32) | (ull)(~ro);
        ull red = key;
        red = dpp_u64max_step<0x111>(red);
        red = dpp_u64max_step<0x112>(red);
        red = dpp_u64max_step<0x114>(red);
        red = dpp_u64max_step<0x118>(red);
        const unsigned wlo = (unsigned)__builtin_amdgcn_readlane((int)(unsigned)red, 63);
        const unsigned whi = (unsigned)__builtin_amdgcn_readlane((int)(unsigned)(red >> 32), 63);
        const ull wk = ((ull)whi << 32) | (ull)wlo;
        const ull hm = __ballot(key == wk);
        const int hl = (int)__builtin_ctzll(hm);       // a lane holding the winner record
        const float qx = __int_as_float(__builtin_amdgcn_readlane(__float_as_int(rf.y), hl));
        const float qy = __int_as_float(__builtin_amdgcn_readlane(__float_as_int(rf.z), hl));
        const float qz = __int_as_float(__builtin_amdgcn_readlane(__float_as_int(rf.w), hl));
        if (t == 0) {
            const int s3 = (i & 1023) * 3;
            s_pick[s3] = qx; s_pick[s3 + 1] = qy; s_pick[s3 + 2] = qz;
        }

        // ---- wave-level slab prune: skip update iff provably all no-ops ----
        const float dxq = fabsf(qx - cx);
        bool active = true;
        if (dxq > hw_safe) {
            const float lb = dxq - hw_safe;            // conservative lower bound
            active = (lb * lb <= my_wval);
        }
        if (active) {
            const v2f nqx2 = (v2f){-qx, -qx};
            const v2f nqy2 = (v2f){-qy, -qy};
            const v2f nqz2 = (v2f){-qz, -qz};
            bv = -1.0f;
#pragma unroll
            for (int u = 0; u < 8; ++u) {
                const float4 xy = s_xy4[t * 9 + u];
                const v2f xp = (v2f){xy.x, xy.y};      // {x0,x1}
                const v2f yp = (v2f){xy.z, xy.w};      // {y0,y1}
                const v2f dx = pk_add(xp, nqx2);       // exact x - qx
                const v2f dy = pk_add(yp, nqy2);
                const v2f dz = pk_add(zp[u], nqz2);
                const v2f m1 = pk_mul(dx, dx);
                const v2f m2 = pk_mul(dy, dy);
                const v2f m3 = pk_mul(dz, dz);
                const v2f s = pk_add(pk_add(m1, m2), m3);  // ((x²+y²)+z²) exact order
                d2[u] = __builtin_elementwise_min(d2[u], s);
                bv = fmaxf(bv, fmaxf(d2[u].x, d2[u].y));
            }
            EXTRACT_RECORD();                          // refresh record (SGPRs)
        }
        if (lane == 0) {
            s_recf[1 - par][wv] = make_float4(my_wval, my_qx, my_qy, my_qz);
            s_reco[1 - par][wv] = my_orig;
        }
    }

    // final flush: picks 3584..4095 (ring half b=512) + n_o scalar
    __syncthreads();
    {
        const int base3 = 3584 * 3;
        const int b3 = 512 * 3;
        out[base3 + t] = s_pick[b3 + t];
        if (t < 512) out[base3 + 1024 + t] = s_pick[b3 + 1024 + t];
        if (t == 0) out[12288 + 786432] = 4096.0f;
    }
}

// ---------------------------------------------------------------------------
// Kernel 2 (R15): fused knn + vn — the validated R14 consumer body as its own
// dispatch. 256 blocks x 1024 threads x 16 queries: one knn round (wave per
// query, nn in LDS), two vn rounds (8 queries each). No nn global round-trip,
// one launch gap instead of two.
// ---------------------------------------------------------------------------
__global__ __launch_bounds__(1024)
void knnvn_kernel(const float* __restrict__ p, const float* __restrict__ x,
                  const float* __restrict__ Wf, const float* __restrict__ Wd,
                  float* __restrict__ out) {
    __shared__ __align__(16) char SMEM[133120];
    float* sWf = (float*)SMEM;                         // 16 KB  [c*64+o]
    float* sWd = (float*)(SMEM + 16384);               // 16 KB
    float* sg  = (float*)(SMEM + 32768);               // 96 KB  8 q x 16 k x 192
    int*  s_nn = (int*)(SMEM + 131072);                // 1 KB   16 q x 16

    const int t = threadIdx.x;
    const int lane = t & 63, wv = t >> 6;
    const int qbase = (int)blockIdx.x * 16;            // 256 blocks x 16 = 4096

    for (int u = t; u < CIN * COUT; u += 1024) {
        const int o = u >> 6, c = u & 63;
        sWf[c * 64 + o] = Wf[u];
        sWd[c * 64 + o] = Wd[u];
    }

    // ---- knn: one wave per query, results into LDS ----
    {
        const int m = qbase + wv;
        const float qx = out[3 * m], qy = out[3 * m + 1], qz = out[3 * m + 2];
        const float qq2 = __fadd_rn(__fadd_rn(__fmul_rn(qx, qx), __fmul_rn(qy, qy)),
                                    __fmul_rn(qz, qz));
        float D[16]; int I[16];
#pragma unroll
        for (int s = 0; s < 16; ++s) { D[s] = FLT_MAX; I[s] = 0x7fffffff; }
        for (int c = 0; c < N_PTS / 64; ++c) {
            const int j = c * 64 + lane;
            const float px = p[3 * j], py = p[3 * j + 1], pz = p[3 * j + 2];
            const float pp = __fadd_rn(__fadd_rn(__fmul_rn(px, px), __fmul_rn(py, py)),
                                       __fmul_rn(pz, pz));
            const float qp = __fadd_rn(__fadd_rn(__fmul_rn(qx, px), __fmul_rn(qy, py)),
                                       __fmul_rn(qz, pz));
            const float d = __fadd_rn(__fsub_rn(qq2, __fmul_rn(2.0f, qp)), pp);
            if (d < D[15]) {
                D[15] = d; I[15] = j;
#pragma unroll
                for (int s = 15; s > 0; --s) {
                    if (D[s] < D[s - 1]) {
                        float tf = D[s]; D[s] = D[s - 1]; D[s - 1] = tf;
                        int   ti = I[s]; I[s] = I[s - 1]; I[s - 1] = ti;
                    }
                }
            }
        }
        int myout = 0;
        for (int r = 0; r < 16; ++r) {
            float v = D[0]; int ix = I[0]; int bl = lane;
#pragma unroll
            for (int off = 1; off < 64; off <<= 1) {
                float ov = __shfl_xor(v, off);
                int   oi = __shfl_xor(ix, off);
                int   ol = __shfl_xor(bl, off);
                if (ov < v || (ov == v && oi < ix)) { v = ov; ix = oi; bl = ol; }
            }
            if (lane == bl) {
#pragma unroll
                for (int s = 0; s < 15; ++s) { D[s] = D[s + 1]; I[s] = I[s + 1]; }
                D[15] = FLT_MAX; I[15] = 0x7fffffff;
            }
            if (lane == r) myout = ix;
        }
        if (lane < K_NN) s_nn[wv * K_NN + lane] = myout;
    }
    __syncthreads();

    // ---- vn: 8 queries per round, thread (qi,o) in [0,512) ----
    float* xo = out + 12288;
    for (int r0 = 0; r0 < 16; r0 += 8) {
        __syncthreads();                               // protect sg reuse
        for (int idx = t; idx < 8 * K_NN * 192; idx += 1024) {
            const int pair = idx / 192;                // qi*16 + k
            const int c3 = idx - pair * 192;
            const int jn = s_nn[(r0 + (pair >> 4)) * K_NN + (pair & 15)];
            sg[idx] = x[jn * 192 + c3];
        }
        __syncthreads();
        if (t < 512) {
            const int qi = t >> 6, o = t & 63;
            const float* g = &sg[qi * K_NN * 192];
            float a0 = 0.0f, a1 = 0.0f, a2 = 0.0f;
            for (int k = 0; k < K_NN; ++k) {
                const float* gk = &g[k * 192];
                float q0 = 0.0f, q1 = 0.0f, q2 = 0.0f;
                float d0 = 0.0f, d1 = 0.0f, d2v = 0.0f;
#pragma unroll 8
                for (int c = 0; c < CIN; ++c) {
                    const float wf = sWf[c * 64 + o];
                    const float wd = sWd[c * 64 + o];
                    const float g0 = gk[c * 3], g1 = gk[c * 3 + 1], g2 = gk[c * 3 + 2];
                    q0 = fmaf(wf, g0, q0); q1 = fmaf(wf, g1, q1); q2 = fmaf(wf, g2, q2);
                    d0 = fmaf(wd, g0, d0); d1 = fmaf(wd, g1, d1); d2v = fmaf(wd, g2, d2v);
                }
                const float dot = q0 * d0 + q1 * d1 + q2 * d2v;
                const float dns = d0 * d0 + d1 * d1 + d2v * d2v + 1e-6f;
                const float f = (dot >= 0.0f) ? 0.0f : 0.8f * (dot / dns);
                a0 += q0 - f * d0;
                a1 += q1 - f * d1;
                a2 += q2 - f * d2v;
            }
            const int m = qbase + r0 + qi;
            xo[(o * 3 + 0) * M_PTS + m] = a0 * 0.0625f;
            xo[(o * 3 + 1) * M_PTS + m] = a1 * 0.0625f;
            xo[(o * 3 + 2) * M_PTS + m] = a2 * 0.0625f;
        }
    }
}

// ---------------------------------------------------------------------------
extern "C" void kernel_launch(void* const* d_in, const int* in_sizes, int n_in,
                              void* d_out, int out_size, void* d_ws, size_t ws_size,
                              hipStream_t stream) {
    const float* p  = (const float*)d_in[0];
    const float* x  = (const float*)d_in[1];
    const float* Wf = (const float*)d_in[2];
    const float* Wd = (const float*)d_in[3];
    float* out = (float*)d_out;

    fps_kernel<<<1, 1024, 0, stream>>>(p, out);
    knnvn_kernel<<<256, 1024, 0, stream>>>(p, x, Wf, Wd, out);
}

// Round 16
// 5541.808 us; speedup vs baseline: 1.0801x; 1.0003x over previous
//
#include <hip/hip_runtime.h>
#include <float.h>

#define N_PTS 16384
#define M_PTS 4096
#define K_NN  16
#define CIN   64
#define COUT  64

typedef float v2f __attribute__((ext_vector_type(2)));
typedef unsigned long long ull;

// Exact f32 rounding to match numpy/jax: ((dx*dx + dy*dy) + dz*dz), no fma contraction.
__device__ __forceinline__ float dist2_exact(float ax, float ay, float az,
                                             float bx, float by, float bz) {
    float dx = __fsub_rn(ax, bx);
    float dy = __fsub_rn(ay, by);
    float dz = __fsub_rn(az, bz);
    return __fadd_rn(__fadd_rn(__fmul_rn(dx, dx), __fmul_rn(dy, dy)), __fmul_rn(dz, dz));
}

// Packed f32 ops via inline asm (v2f codegen otherwise scalarizes — R6 evidence).
__device__ __forceinline__ v2f pk_add(v2f a, v2f b) {
    v2f d; asm("v_pk_add_f32 %0, %1, %2" : "=v"(d) : "v"(a), "v"(b)); return d;
}
__device__ __forceinline__ v2f pk_mul(v2f a, v2f b) {
    v2f d; asm("v_pk_mul_f32 %0, %1, %2" : "=v"(d) : "v"(a), "v"(b)); return d;
}

// ---- DPP wave-64 reduction steps (idempotent ops -> full masks safe) ----
template <int CTRL>
__device__ __forceinline__ float dpp_fmax_step(float x) {
    int xi = __float_as_int(x);
    int yi = __builtin_amdgcn_update_dpp(xi, xi, CTRL, 0xf, 0xf, false);
    return fmaxf(x, __int_as_float(yi));
}
template <int CTRL>
__device__ __forceinline__ unsigned dpp_umin_step(unsigned x) {
    int xi = (int)x;
    unsigned y = (unsigned)__builtin_amdgcn_update_dpp(xi, xi, CTRL, 0xf, 0xf, false);
    return y < x ? y : x;
}
template <int CTRL>
__device__ __forceinline__ ull dpp_u64max_step(ull x) {
    int lo = (int)(unsigned)x;
    int hi = (int)(unsigned)(x >> 32);
    unsigned olo = (unsigned)__builtin_amdgcn_update_dpp(lo, lo, CTRL, 0xf, 0xf, false);
    unsigned ohi = (unsigned)__builtin_amdgcn_update_dpp(hi, hi, CTRL, 0xf, 0xf, false);
    ull o = ((ull)ohi << 32) | (ull)olo;
    return o > x ? o : x;
}
__device__ __forceinline__ unsigned wave_umin(unsigned x) {
    x = dpp_umin_step<0x111>(x);
    x = dpp_umin_step<0x112>(x);
    x = dpp_umin_step<0x114>(x);
    x = dpp_umin_step<0x118>(x);
    x = dpp_umin_step<0x142>(x);
    x = dpp_umin_step<0x143>(x);
    return (unsigned)__builtin_amdgcn_readlane((int)x, 63);
}

// Per-wave record extraction (R9, unchanged): wave max of d2 -> SGPR record.
#define EXTRACT_RECORD()                                                          \
    {                                                                             \
        float _w = bv;                                                            \
        _w = dpp_fmax_step<0x111>(_w);                                            \
        _w = dpp_fmax_step<0x112>(_w);                                            \
        _w = dpp_fmax_step<0x114>(_w);                                            \
        _w = dpp_fmax_step<0x118>(_w);                                            \
        _w = dpp_fmax_step<0x142>(_w);                                            \
        _w = dpp_fmax_step<0x143>(_w);                                            \
        my_wval = __int_as_float(__builtin_amdgcn_readlane(__float_as_int(_w), 63)); \
        unsigned _kk = 0xffffffffu;                                               \
        float _cz = 0.0f;                                                         \
        _Pragma("unroll")                                                         \
        for (int _u = 0; _u < 16; ++_u) {                                         \
            const float _dv = (_u & 1) ? d2[_u >> 1].y : d2[_u >> 1].x;           \
            const unsigned _og = (_u & 1) ? (opk[_u >> 1] >> 16)                  \
                                          : (opk[_u >> 1] & 0xffffu);             \
            const unsigned _ky = (_og << 4) | (unsigned)_u;                       \
            const unsigned _uk = (_dv == my_wval) ? _ky : 0xffffffffu;            \
            if (_uk < _kk) {                                                      \
                _kk = _uk;                                                        \
                _cz = (_u & 1) ? zp[_u >> 1].y : zp[_u >> 1].x;                   \
            }                                                                     \
        }                                                                         \
        const unsigned _wkk = wave_umin(_kk);                                     \
        const ull _m = __ballot(_kk == _wkk);                                     \
        const int _wl = (int)__builtin_ctzll(_m);                                 \
        my_orig = _wkk >> 4;                                                      \
        const int _slot = (int)(_wkk & 15u);                                      \
        const int _wt = wv * 64 + _wl;                                            \
        const float4 _xy = s_xy4[_wt * 9 + (_slot >> 1)];                         \
        const float _qx = (_slot & 1) ? _xy.y : _xy.x;                            \
        const float _qy = (_slot & 1) ? _xy.w : _xy.z;                            \
        my_qx = __int_as_float(__builtin_amdgcn_readfirstlane(__float_as_int(_qx))); \
        my_qy = __int_as_float(__builtin_amdgcn_readfirstlane(__float_as_int(_qy))); \
        my_qz = __int_as_float(__builtin_amdgcn_readlane(__float_as_int(_cz), _wl)); \
    }

// ---------------------------------------------------------------------------
// Kernel 1: furthest point sampling — EXACT R9/R12/R15 kernel, standalone
// dispatch. Measured floor 5150 µs across 4 reproductions; do not touch.
// ---------------------------------------------------------------------------
__global__ __launch_bounds__(1024) void fps_kernel(const float* __restrict__ p,
                                                   float* __restrict__ out) {
#pragma clang fp contract(off)
    const int t = threadIdx.x;
    const int lane = t & 63, wv = t >> 6;
    __shared__ char smem[147456];                      // keys[16384] then s_xy4[1024*9]
    __shared__ float s_pick[1024 * 3];                 // pick ring (12 KB)
    __shared__ float4 s_recf[2][16];                   // {val, qx, qy, qz}
    __shared__ unsigned s_reco[2][16];                 // orig

    ull* keys = (ull*)smem;
    float4* s_xy4 = (float4*)smem;

    // ---- Phase A: bitonic sort by x (keys unique via idx bits) ----
    for (int u = 0; u < 16; ++u) {
        const int j = u * 1024 + t;
        keys[j] = ((ull)__float_as_uint(p[3 * j]) << 32) | (unsigned)j;
    }
    __syncthreads();
    for (int k = 2; k <= N_PTS; k <<= 1) {
        for (int j = k >> 1; j > 0; j >>= 1) {
            for (int e = 0; e < 8; ++e) {
                const int c = e * 1024 + t;
                const int i1 = 2 * c - (c & (j - 1));
                const int i2 = i1 + j;
                const ull a = keys[i1], b = keys[i2];
                const bool up = ((i1 & k) == 0);
                if ((a > b) == up) { keys[i1] = b; keys[i2] = a; }
            }
            __syncthreads();
        }
    }

    // read own 16 sorted keys -> packed original indices (8 regs)
    unsigned opk[8];
#pragma unroll
    for (int u = 0; u < 8; ++u) {
        const ull a = keys[t * 16 + 2 * u];
        const ull b = keys[t * 16 + 2 * u + 1];
        opk[u] = ((unsigned)a & 0xffffu) | (((unsigned)b & 0xffffu) << 16);
    }
    __syncthreads();                                   // all key reads done before overwrite

    // ---- gather coords, build LDS xy ({x0,x1,y0,y1}) + reg z/d2, init bv ----
    v2f zp[8], d2[8];
    const float q0x = p[0], q0y = p[1], q0z = p[2];
    float bv = -1.0f;
    float xf = 0.0f, xl = 0.0f;
#pragma unroll
    for (int u = 0; u < 8; ++u) {
        const int o0 = (int)(opk[u] & 0xffffu), o1 = (int)(opk[u] >> 16);
        const float x0 = p[3 * o0], y0 = p[3 * o0 + 1], z0 = p[3 * o0 + 2];
        const float x1 = p[3 * o1], y1 = p[3 * o1 + 1], z1 = p[3 * o1 + 2];
        s_xy4[t * 9 + u] = make_float4(x0, x1, y0, y1);
        zp[u] = (v2f){z0, z1};
        d2[u] = (v2f){dist2_exact(x0, y0, z0, q0x, q0y, q0z),
                      dist2_exact(x1, y1, z1, q0x, q0y, q0z)};
        bv = fmaxf(bv, fmaxf(d2[u].x, d2[u].y));
        if (u == 0) xf = x0;
        if (u == 7) xl = x1;
    }
    const float wxmin = __int_as_float(__builtin_amdgcn_readlane(__float_as_int(xf), 0));
    const float wxmax = __int_as_float(__builtin_amdgcn_readlane(__float_as_int(xl), 63));
    const float cx = 0.5f * (wxmin + wxmax);
    const float hw_safe = 0.5f * (wxmax - wxmin) + 1e-5f;

    float my_wval, my_qx, my_qy, my_qz;
    unsigned my_orig;
    EXTRACT_RECORD();
    if (lane == 0) {
        s_recf[1][wv] = make_float4(my_wval, my_qx, my_qy, my_qz);
        s_reco[1][wv] = my_orig;
    }
    if (t == 0) { s_pick[0] = q0x; s_pick[1] = q0y; s_pick[2] = q0z; }

    for (int i = 1; i < M_PTS; ++i) {
        const int par = i & 1;
        __syncthreads();                               // the ONE barrier per iteration

        // ring flush: once per 512 iters, previous 512-block (other ring half)
        if ((i & 511) == 0) {
            const int b = (i - 512) & 1023;
            const int base3 = (i - 512) * 3;
            out[base3 + t] = s_pick[b * 3 + t];
            if (t < 512) out[base3 + 1024 + t] = s_pick[b * 3 + 1024 + t];
        }

        // global winner from the 16 records: u64 key = (val_bits<<32 | ~orig)
        const int r = lane & 15;
        const float4 rf = s_recf[par][r];
        const unsigned ro = s_reco[par][r];
        ull key = ((ull)__float_as_uint(rf.x) << 32) | (ull)(~ro);
        ull red = key;
        red = dpp_u64max_step<0x111>(red);
        red = dpp_u64max_step<0x112>(red);
        red = dpp_u64max_step<0x114>(red);
        red = dpp_u64max_step<0x118>(red);
        const unsigned wlo = (unsigned)__builtin_amdgcn_readlane((int)(unsigned)red, 63);
        const unsigned whi = (unsigned)__builtin_amdgcn_readlane((int)(unsigned)(red >> 32), 63);
        const ull wk = ((ull)whi << 32) | (ull)wlo;
        const ull hm = __ballot(key == wk);
        const int hl = (int)__builtin_ctzll(hm);       // a lane holding the winner record
        const float qx = __int_as_float(__builtin_amdgcn_readlane(__float_as_int(rf.y), hl));
        const float qy = __int_as_float(__builtin_amdgcn_readlane(__float_as_int(rf.z), hl));
        const float qz = __int_as_float(__builtin_amdgcn_readlane(__float_as_int(rf.w), hl));
        if (t == 0) {
            const int s3 = (i & 1023) * 3;
            s_pick[s3] = qx; s_pick[s3 + 1] = qy; s_pick[s3 + 2] = qz;
        }

        // ---- wave-level slab prune: skip update iff provably all no-ops ----
        const float dxq = fabsf(qx - cx);
        bool active = true;
        if (dxq > hw_safe) {
            const float lb = dxq - hw_safe;            // conservative lower bound
            active = (lb * lb <= my_wval);
        }
        if (active) {
            const v2f nqx2 = (v2f){-qx, -qx};
            const v2f nqy2 = (v2f){-qy, -qy};
            const v2f nqz2 = (v2f){-qz, -qz};
            bv = -1.0f;
#pragma unroll
            for (int u = 0; u < 8; ++u) {
                const float4 xy = s_xy4[t * 9 + u];
                const v2f xp = (v2f){xy.x, xy.y};      // {x0,x1}
                const v2f yp = (v2f){xy.z, xy.w};      // {y0,y1}
                const v2f dx = pk_add(xp, nqx2);       // exact x - qx
                const v2f dy = pk_add(yp, nqy2);
                const v2f dz = pk_add(zp[u], nqz2);
                const v2f m1 = pk_mul(dx, dx);
                const v2f m2 = pk_mul(dy, dy);
                const v2f m3 = pk_mul(dz, dz);
                const v2f s = pk_add(pk_add(m1, m2), m3);  // ((x²+y²)+z²) exact order
                d2[u] = __builtin_elementwise_min(d2[u], s);
                bv = fmaxf(bv, fmaxf(d2[u].x, d2[u].y));
            }
            EXTRACT_RECORD();                          // refresh record (SGPRs)
        }
        if (lane == 0) {
            s_recf[1 - par][wv] = make_float4(my_wval, my_qx, my_qy, my_qz);
            s_reco[1 - par][wv] = my_orig;
        }
    }

    // final flush: picks 3584..4095 (ring half b=512) + n_o scalar
    __syncthreads();
    {
        const int base3 = 3584 * 3;
        const int b3 = 512 * 3;
        out[base3 + t] = s_pick[b3 + t];
        if (t < 512) out[base3 + 1024 + t] = s_pick[b3 + 1024 + t];
        if (t == 0) out[12288 + 786432] = 4096.0f;
    }
}

// ---------------------------------------------------------------------------
// Kernel 2 (R16): fused knn + vn. knn unchanged (bit-exactness). vn k-split:
// stage k=[0,8) for ALL 16 queries (96 KB), compute with all 1024 threads
// (thread = (qi,o), 16x64), then k=[8,16). Per-k leaky-ReLU makes k-split
// accumulation exact. Halves vn wall-time vs R15's half-idle 2-round form.
// ---------------------------------------------------------------------------
__global__ __launch_bounds__(1024)
void knnvn_kernel(const float* __restrict__ p, const float* __restrict__ x,
                  const float* __restrict__ Wf, const float* __restrict__ Wd,
                  float* __restrict__ out) {
    __shared__ __align__(16) char SMEM[133120];
    float* sWf = (float*)SMEM;                         // 16 KB  [c*64+o]
    float* sWd = (float*)(SMEM + 16384);               // 16 KB
    float* sg  = (float*)(SMEM + 32768);               // 96 KB  16 q x 8 k x 192
    int*  s_nn = (int*)(SMEM + 131072);                // 1 KB   16 q x 16

    const int t = threadIdx.x;
    const int lane = t & 63, wv = t >> 6;
    const int qbase = (int)blockIdx.x * 16;            // 256 blocks x 16 = 4096

    for (int u = t; u < CIN * COUT; u += 1024) {
        const int o = u >> 6, c = u & 63;
        sWf[c * 64 + o] = Wf[u];
        sWd[c * 64 + o] = Wd[u];
    }

    // ---- knn: one wave per query, results into LDS (exact top_k semantics) ----
    {
        const int m = qbase + wv;
        const float qx = out[3 * m], qy = out[3 * m + 1], qz = out[3 * m + 2];
        const float qq2 = __fadd_rn(__fadd_rn(__fmul_rn(qx, qx), __fmul_rn(qy, qy)),
                                    __fmul_rn(qz, qz));
        float D[16]; int I[16];
#pragma unroll
        for (int s = 0; s < 16; ++s) { D[s] = FLT_MAX; I[s] = 0x7fffffff; }
        for (int c = 0; c < N_PTS / 64; ++c) {
            const int j = c * 64 + lane;
            const float px = p[3 * j], py = p[3 * j + 1], pz = p[3 * j + 2];
            const float pp = __fadd_rn(__fadd_rn(__fmul_rn(px, px), __fmul_rn(py, py)),
                                       __fmul_rn(pz, pz));
            const float qp = __fadd_rn(__fadd_rn(__fmul_rn(qx, px), __fmul_rn(qy, py)),
                                       __fmul_rn(qz, pz));
            const float d = __fadd_rn(__fsub_rn(qq2, __fmul_rn(2.0f, qp)), pp);
            if (d < D[15]) {
                D[15] = d; I[15] = j;
#pragma unroll
                for (int s = 15; s > 0; --s) {
                    if (D[s] < D[s - 1]) {
                        float tf = D[s]; D[s] = D[s - 1]; D[s - 1] = tf;
                        int   ti = I[s]; I[s] = I[s - 1]; I[s - 1] = ti;
                    }
                }
            }
        }
        int myout = 0;
        for (int r = 0; r < 16; ++r) {
            float v = D[0]; int ix = I[0]; int bl = lane;
#pragma unroll
            for (int off = 1; off < 64; off <<= 1) {
                float ov = __shfl_xor(v, off);
                int   oi = __shfl_xor(ix, off);
                int   ol = __shfl_xor(bl, off);
                if (ov < v || (ov == v && oi < ix)) { v = ov; ix = oi; bl = ol; }
            }
            if (lane == bl) {
#pragma unroll
                for (int s = 0; s < 15; ++s) { D[s] = D[s + 1]; I[s] = I[s + 1]; }
                D[15] = FLT_MAX; I[15] = 0x7fffffff;
            }
            if (lane == r) myout = ix;
        }
        if (lane < K_NN) s_nn[wv * K_NN + lane] = myout;
    }

    // ---- vn, k-split: all 1024 threads = (qi 0..15, o 0..63) ----
    const int qi = t >> 6, o = t & 63;
    float a0 = 0.0f, a1 = 0.0f, a2 = 0.0f;
#pragma unroll
    for (int half = 0; half < 2; ++half) {
        __syncthreads();                               // nn ready / sg reuse safe
        // stage k in [half*8, half*8+8) for all 16 queries: 24576 floats
        for (int idx = t; idx < 16 * 8 * 192; idx += 1024) {
            const int pair = idx / 192;                // qj*8 + kk
            const int c3 = idx - pair * 192;
            const int jn = s_nn[(pair >> 3) * K_NN + half * 8 + (pair & 7)];
            sg[idx] = x[jn * 192 + c3];
        }
        __syncthreads();
        for (int kk = 0; kk < 8; ++kk) {
            const float* gk = &sg[(qi * 8 + kk) * 192];
            float q0 = 0.0f, q1 = 0.0f, q2 = 0.0f;
            float d0 = 0.0f, d1 = 0.0f, d2v = 0.0f;
#pragma unroll 8
            for (int c = 0; c < CIN; ++c) {
                const float wf = sWf[c * 64 + o];
                const float wd = sWd[c * 64 + o];
                const float g0 = gk[c * 3], g1 = gk[c * 3 + 1], g2 = gk[c * 3 + 2];
                q0 = fmaf(wf, g0, q0); q1 = fmaf(wf, g1, q1); q2 = fmaf(wf, g2, q2);
                d0 = fmaf(wd, g0, d0); d1 = fmaf(wd, g1, d1); d2v = fmaf(wd, g2, d2v);
            }
            const float dot = q0 * d0 + q1 * d1 + q2 * d2v;
            const float dns = d0 * d0 + d1 * d1 + d2v * d2v + 1e-6f;
            const float f = (dot >= 0.0f) ? 0.0f : 0.8f * (dot / dns);
            a0 += q0 - f * d0;
            a1 += q1 - f * d1;
            a2 += q2 - f * d2v;
        }
    }
    float* xo = out + 12288;
    const int m = qbase + qi;
    xo[(o * 3 + 0) * M_PTS + m] = a0 * 0.0625f;        // mean over 16
    xo[(o * 3 + 1) * M_PTS + m] = a1 * 0.0625f;
    xo[(o * 3 + 2) * M_PTS + m] = a2 * 0.0625f;
}

// ---------------------------------------------------------------------------
extern "C" void kernel_launch(void* const* d_in, const int* in_sizes, int n_in,
                              void* d_out, int out_size, void* d_ws, size_t ws_size,
                              hipStream_t stream) {
    const float* p  = (const float*)d_in[0];
    const float* x  = (const float*)d_in[1];
    const float* Wf = (const float*)d_in[2];
    const float* Wd = (const float*)d_in[3];
    float* out = (float*)d_out;

    fps_kernel<<<1, 1024, 0, stream>>>(p, out);
    knnvn_kernel<<<256, 1024, 0, stream>>>(p, x, Wf, Wd, out);
}